// Round 1
// baseline (780.260 us; speedup 1.0000x reference)
//
#include <hip/hip_runtime.h>

#define DD 64

// ---------------------------------------------------------------------------
// Detect whether edge_index arrived as int64 (little-endian high words == 0)
// or int32. Deterministic, runs every call.
// ---------------------------------------------------------------------------
__global__ void detect_i64_kernel(const unsigned int* __restrict__ p, int nPairs,
                                  int* __restrict__ flag) {
  if (blockIdx.x == 0 && threadIdx.x == 0) {
    int is64 = 1;
    int lim = nPairs < 128 ? nPairs : 128;
    for (int i = 0; i < lim; ++i) {
      if (p[2 * i + 1] != 0u) { is64 = 0; break; }
    }
    *flag = is64;
  }
}

__global__ void init_deg_kernel(int* __restrict__ deg, int n) {
  int i = blockIdx.x * blockDim.x + threadIdx.x;
  if (i < n) deg[i] = 1;   // self-loop
}

__global__ void convert_count_kernel(const void* __restrict__ eidx, int E,
                                     int* __restrict__ src32, int* __restrict__ dst32,
                                     int* __restrict__ deg, const int* __restrict__ flag) {
  int e = blockIdx.x * blockDim.x + threadIdx.x;
  if (e >= E) return;
  int s, d;
  if (*flag) {
    const long long* p = (const long long*)eidx;
    s = (int)p[e];
    d = (int)p[e + E];
  } else {
    const int* p = (const int*)eidx;
    s = p[e];
    d = p[e + E];
  }
  src32[e] = s;
  dst32[e] = d;
  atomicAdd(&deg[d], 1);
}

__global__ void dinv_kernel(const int* __restrict__ deg, float* __restrict__ dinv, int n) {
  int i = blockIdx.x * blockDim.x + threadIdx.x;
  if (i < n) dinv[i] = rsqrtf((float)deg[i]);
}

// ---- hierarchical exclusive scan of deg -> offs (tile = 1024) --------------
__global__ void scan_tile_kernel(const int* __restrict__ deg, int* __restrict__ incl,
                                 int* __restrict__ bsum, int n) {
  __shared__ int s[1024];
  int tid = threadIdx.x;
  int i = blockIdx.x * 1024 + tid;
  int v = (i < n) ? deg[i] : 0;
  s[tid] = v;
  __syncthreads();
  for (int off = 1; off < 1024; off <<= 1) {
    int tv = (tid >= off) ? s[tid - off] : 0;
    __syncthreads();
    s[tid] += tv;
    __syncthreads();
  }
  if (i < n) incl[i] = s[tid];
  if (tid == 1023) bsum[blockIdx.x] = s[1023];
}

__global__ void scan_blocks_kernel(const int* __restrict__ bsum, int* __restrict__ boff,
                                   int nb, int* __restrict__ total_out) {
  if (blockIdx.x == 0 && threadIdx.x == 0) {
    int run = 0;
    for (int i = 0; i < nb; ++i) { boff[i] = run; run += bsum[i]; }
    *total_out = run;   // offs[n]
  }
}

__global__ void scan_final_kernel(const int* __restrict__ incl, const int* __restrict__ deg,
                                  const int* __restrict__ boff, int* __restrict__ offs,
                                  int* __restrict__ cursor, int n) {
  int i = blockIdx.x * blockDim.x + threadIdx.x;
  if (i >= n) return;
  int e = incl[i] - deg[i] + boff[i >> 10];
  offs[i] = e;
  cursor[i] = e;
}

// ---- CSR fill: edges then self-loops ---------------------------------------
__global__ void scatter_kernel(const int* __restrict__ src32, const int* __restrict__ dst32,
                               const float* __restrict__ dinv, int* __restrict__ cursor,
                               int* __restrict__ col, float* __restrict__ val, int E, int n) {
  int e = blockIdx.x * blockDim.x + threadIdx.x;
  if (e < E) {
    int s = src32[e], d = dst32[e];
    int pos = atomicAdd(&cursor[d], 1);
    col[pos] = s;
    val[pos] = dinv[s] * dinv[d];
  } else if (e < E + n) {
    int m = e - E;
    int pos = atomicAdd(&cursor[m], 1);
    col[pos] = m;
    float dv = dinv[m];
    val[pos] = dv * dv;
  }
}

// ---- dense GEMM: T = H @ W (+bias, relu if fuse) ---------------------------
// block = 256 threads, 64 rows per block; W staged in LDS padded [64][68].
__global__ __launch_bounds__(256) void gemm_kernel(
    const float* __restrict__ H, const float* __restrict__ W,
    const float* __restrict__ bias, float* __restrict__ T,
    int n, int fuse) {
  __shared__ float Ws[64][68];
  int tid = threadIdx.x;
  for (int i = tid; i < 1024; i += 256) {
    float4 wv = ((const float4*)W)[i];
    int row = i >> 4, cq = i & 15;
    *reinterpret_cast<float4*>(&Ws[row][cq << 2]) = wv;
  }
  __syncthreads();
  int r = tid >> 2, cg = tid & 3;
  long long row = (long long)blockIdx.x * 64 + r;
  if (row >= n) return;

  const float4* xp = reinterpret_cast<const float4*>(H + (size_t)row * DD);
  float xr[64];
#pragma unroll
  for (int i = 0; i < 16; ++i) {
    float4 v = xp[i];
    xr[4 * i + 0] = v.x; xr[4 * i + 1] = v.y;
    xr[4 * i + 2] = v.z; xr[4 * i + 3] = v.w;
  }
  float acc[16];
#pragma unroll
  for (int i = 0; i < 16; ++i) acc[i] = 0.f;

#pragma unroll
  for (int k = 0; k < 64; ++k) {
    float xv = xr[k];
#pragma unroll
    for (int i = 0; i < 4; ++i) {
      float4 wv = *reinterpret_cast<const float4*>(&Ws[k][(cg << 4) + (i << 2)]);
      acc[4 * i + 0] = fmaf(xv, wv.x, acc[4 * i + 0]);
      acc[4 * i + 1] = fmaf(xv, wv.y, acc[4 * i + 1]);
      acc[4 * i + 2] = fmaf(xv, wv.z, acc[4 * i + 2]);
      acc[4 * i + 3] = fmaf(xv, wv.w, acc[4 * i + 3]);
    }
  }

  float* outp = T + (size_t)row * DD + (cg << 4);
#pragma unroll
  for (int i = 0; i < 4; ++i) {
    float4 o = make_float4(acc[4 * i + 0], acc[4 * i + 1], acc[4 * i + 2], acc[4 * i + 3]);
    if (fuse) {
      const float4 bv = *reinterpret_cast<const float4*>(bias + (cg << 4) + (i << 2));
      o.x = fmaxf(o.x + bv.x, 0.f);
      o.y = fmaxf(o.y + bv.y, 0.f);
      o.z = fmaxf(o.z + bv.z, 0.f);
      o.w = fmaxf(o.w + bv.w, 0.f);
    }
    reinterpret_cast<float4*>(outp)[i] = o;
  }
}

// ---- CSR aggregation: out[n,:] = sum_j val[j]*T[col[j],:] + b (relu opt) ---
// one wave (64 lanes) per node, lane = feature dim. No atomics.
__global__ __launch_bounds__(256) void aggregate_kernel(
    const float* __restrict__ T, const int* __restrict__ offs,
    const int* __restrict__ col, const float* __restrict__ val,
    const float* __restrict__ bias, float* __restrict__ out,
    int n, int relu) {
  int gid = blockIdx.x * blockDim.x + threadIdx.x;
  int wid = gid >> 6;
  int lane = threadIdx.x & 63;
  if (wid >= n) return;
  int j0 = offs[wid], j1 = offs[wid + 1];
  float acc = 0.f;
  int j = j0;
  for (; j + 4 <= j1; j += 4) {
    int c0 = col[j], c1 = col[j + 1], c2 = col[j + 2], c3 = col[j + 3];
    float v0 = val[j], v1 = val[j + 1], v2 = val[j + 2], v3 = val[j + 3];
    float f0 = T[(size_t)c0 * DD + lane];
    float f1 = T[(size_t)c1 * DD + lane];
    float f2 = T[(size_t)c2 * DD + lane];
    float f3 = T[(size_t)c3 * DD + lane];
    acc = fmaf(v0, f0, acc);
    acc = fmaf(v1, f1, acc);
    acc = fmaf(v2, f2, acc);
    acc = fmaf(v3, f3, acc);
  }
  for (; j < j1; ++j)
    acc = fmaf(val[j], T[(size_t)col[j] * DD + lane], acc);
  acc += bias[lane];
  if (relu) acc = fmaxf(acc, 0.f);
  out[(size_t)wid * DD + lane] = acc;
}

// ---------------------------------------------------------------------------
extern "C" void kernel_launch(void* const* d_in, const int* in_sizes, int n_in,
                              void* d_out, int out_size, void* d_ws, size_t ws_size,
                              hipStream_t stream) {
  const float* x   = (const float*)d_in[0];
  const void*  eix = d_in[1];
  const float* Win = (const float*)d_in[2];
  const float* bin = (const float*)d_in[3];
  const float* W1  = (const float*)d_in[4];
  const float* b1  = (const float*)d_in[5];
  const float* W2  = (const float*)d_in[6];
  const float* b2  = (const float*)d_in[7];
  const float* W3  = (const float*)d_in[8];
  const float* b3  = (const float*)d_in[9];

  int n = in_sizes[0] / DD;
  int E = in_sizes[1] / 2;
  int M = E + n;

  char* w = (char*)d_ws;
  auto carve = [&](size_t bytes) {
    char* p = w;
    w += (bytes + 255) & ~(size_t)255;
    return p;
  };
  int*   flag   = (int*)carve(4);
  int*   deg    = (int*)carve((size_t)n * 4);
  float* dinv   = (float*)carve((size_t)n * 4);
  int*   incl   = (int*)carve((size_t)n * 4);
  int*   bsum   = (int*)carve(4096);
  int*   boff   = (int*)carve(4096);
  int*   offs   = (int*)carve((size_t)(n + 1) * 4);
  int*   cursor = (int*)carve((size_t)n * 4);
  int*   src32  = (int*)carve((size_t)E * 4);
  int*   dst32  = (int*)carve((size_t)E * 4);
  int*   col    = (int*)carve((size_t)M * 4);
  float* val    = (float*)carve((size_t)M * 4);
  float* hbuf   = (float*)carve((size_t)n * DD * 4);
  float* tbuf   = (float*)carve((size_t)n * DD * 4);

  int nb = (n + 1023) / 1024;

  detect_i64_kernel<<<1, 64, 0, stream>>>((const unsigned int*)eix, E, flag);
  init_deg_kernel<<<(n + 255) / 256, 256, 0, stream>>>(deg, n);
  convert_count_kernel<<<(E + 255) / 256, 256, 0, stream>>>(eix, E, src32, dst32, deg, flag);
  dinv_kernel<<<(n + 255) / 256, 256, 0, stream>>>(deg, dinv, n);
  scan_tile_kernel<<<nb, 1024, 0, stream>>>(deg, incl, bsum, n);
  scan_blocks_kernel<<<1, 64, 0, stream>>>(bsum, boff, nb, offs + n);
  scan_final_kernel<<<(n + 255) / 256, 256, 0, stream>>>(incl, deg, boff, offs, cursor, n);
  scatter_kernel<<<(M + 255) / 256, 256, 0, stream>>>(src32, dst32, dinv, cursor, col, val, E, n);

  int gemm_grid = (n + 63) / 64;
  int agg_grid  = (n * 64 + 255) / 256;

  // layer 0: h = relu(x @ W_in + b_in)
  gemm_kernel<<<gemm_grid, 256, 0, stream>>>(x, Win, bin, hbuf, n, 1);

  // conv1: h = relu(agg(h @ W1) + b1)
  gemm_kernel<<<gemm_grid, 256, 0, stream>>>(hbuf, W1, nullptr, tbuf, n, 0);
  aggregate_kernel<<<agg_grid, 256, 0, stream>>>(tbuf, offs, col, val, b1, hbuf, n, 1);

  // conv2: h = relu(agg(h @ W2) + b2)
  gemm_kernel<<<gemm_grid, 256, 0, stream>>>(hbuf, W2, nullptr, tbuf, n, 0);
  aggregate_kernel<<<agg_grid, 256, 0, stream>>>(tbuf, offs, col, val, b2, hbuf, n, 1);

  // conv3: out = agg(h @ W3) + b3   (no relu)
  gemm_kernel<<<gemm_grid, 256, 0, stream>>>(hbuf, W3, nullptr, tbuf, n, 0);
  aggregate_kernel<<<agg_grid, 256, 0, stream>>>(tbuf, offs, col, val, b3, (float*)d_out, n, 0);
}

// Round 2
// 466.730 us; speedup vs baseline: 1.6718x; 1.6718x over previous
//
#include <hip/hip_runtime.h>

#define DD 64

// ---------------------------------------------------------------------------
// Detect whether edge_index arrived as int64 (little-endian high words == 0)
// or int32. Deterministic, runs every call.
// ---------------------------------------------------------------------------
__global__ void detect_i64_kernel(const unsigned int* __restrict__ p, int nPairs,
                                  int* __restrict__ flag) {
  if (blockIdx.x == 0 && threadIdx.x == 0) {
    int is64 = 1;
    int lim = nPairs < 128 ? nPairs : 128;
    for (int i = 0; i < lim; ++i) {
      if (p[2 * i + 1] != 0u) { is64 = 0; break; }
    }
    *flag = is64;
  }
}

__global__ void init_deg_kernel(int* __restrict__ deg, int n) {
  int i = blockIdx.x * blockDim.x + threadIdx.x;
  if (i < n) deg[i] = 1;   // self-loop
}

__global__ void convert_count_kernel(const void* __restrict__ eidx, int E,
                                     int* __restrict__ src32, int* __restrict__ dst32,
                                     int* __restrict__ deg, const int* __restrict__ flag) {
  int e = blockIdx.x * blockDim.x + threadIdx.x;
  if (e >= E) return;
  int s, d;
  if (*flag) {
    const long long* p = (const long long*)eidx;
    s = (int)p[e];
    d = (int)p[e + E];
  } else {
    const int* p = (const int*)eidx;
    s = p[e];
    d = p[e + E];
  }
  src32[e] = s;
  dst32[e] = d;
  atomicAdd(&deg[d], 1);
}

__global__ void dinv_kernel(const int* __restrict__ deg, float* __restrict__ dinv, int n) {
  int i = blockIdx.x * blockDim.x + threadIdx.x;
  if (i < n) dinv[i] = rsqrtf((float)deg[i]);
}

// ---- hierarchical exclusive scan of deg -> offs (tile = 1024) --------------
__global__ void scan_tile_kernel(const int* __restrict__ deg, int* __restrict__ incl,
                                 int* __restrict__ bsum, int n) {
  __shared__ int s[1024];
  int tid = threadIdx.x;
  int i = blockIdx.x * 1024 + tid;
  int v = (i < n) ? deg[i] : 0;
  s[tid] = v;
  __syncthreads();
  for (int off = 1; off < 1024; off <<= 1) {
    int tv = (tid >= off) ? s[tid - off] : 0;
    __syncthreads();
    s[tid] += tv;
    __syncthreads();
  }
  if (i < n) incl[i] = s[tid];
  if (tid == 1023) bsum[blockIdx.x] = s[1023];
}

__global__ void scan_blocks_kernel(const int* __restrict__ bsum, int* __restrict__ boff,
                                   int nb, int* __restrict__ total_out) {
  if (blockIdx.x == 0 && threadIdx.x == 0) {
    int run = 0;
    for (int i = 0; i < nb; ++i) { boff[i] = run; run += bsum[i]; }
    *total_out = run;   // offs[n]
  }
}

__global__ void scan_final_kernel(const int* __restrict__ incl, const int* __restrict__ deg,
                                  const int* __restrict__ boff, int* __restrict__ offs,
                                  int* __restrict__ cursor, int n) {
  int i = blockIdx.x * blockDim.x + threadIdx.x;
  if (i >= n) return;
  int e = incl[i] - deg[i] + boff[i >> 10];
  offs[i] = e;
  cursor[i] = e;
}

// ---- CSR fill: edges then self-loops ---------------------------------------
__global__ void scatter_kernel(const int* __restrict__ src32, const int* __restrict__ dst32,
                               const float* __restrict__ dinv, int* __restrict__ cursor,
                               int* __restrict__ col, float* __restrict__ val, int E, int n) {
  int e = blockIdx.x * blockDim.x + threadIdx.x;
  if (e < E) {
    int s = src32[e], d = dst32[e];
    int pos = atomicAdd(&cursor[d], 1);
    col[pos] = s;
    val[pos] = dinv[s] * dinv[d];
  } else if (e < E + n) {
    int m = e - E;
    int pos = atomicAdd(&cursor[m], 1);
    col[pos] = m;
    float dv = dinv[m];
    val[pos] = dv * dv;
  }
}

// ---- dense GEMM: T = H @ W (+bias, relu if fuse) ---------------------------
// block = 256 threads (16x16); 64 rows per block; W and H tile staged in LDS.
// Each thread computes a 4x4 output tile -> acc fits easily in VGPRs (no spill).
__global__ __launch_bounds__(256) void gemm_kernel(
    const float* __restrict__ H, const float* __restrict__ W,
    const float* __restrict__ bias, float* __restrict__ T,
    int n, int fuse) {
  __shared__ float Ws[64][68];
  __shared__ float Hs[64][68];
  int tid = threadIdx.x;
  int row0 = blockIdx.x * 64;

  // stage W (64x64) and H tile (64x64), both padded to 68 floats/row
  for (int i = tid; i < 1024; i += 256) {
    int r = i >> 4, c = (i & 15) << 2;
    float4 wv = ((const float4*)W)[i];
    *reinterpret_cast<float4*>(&Ws[r][c]) = wv;
    float4 hv = make_float4(0.f, 0.f, 0.f, 0.f);
    if (row0 + r < n)
      hv = *reinterpret_cast<const float4*>(H + (size_t)(row0 + r) * DD + c);
    *reinterpret_cast<float4*>(&Hs[r][c]) = hv;
  }
  __syncthreads();

  int tr = tid >> 4, tc = tid & 15;   // 16x16 thread grid
  int r0 = tr << 2, c0 = tc << 2;     // 4x4 tile at (r0, c0)

  float acc[4][4];
#pragma unroll
  for (int i = 0; i < 4; ++i)
#pragma unroll
    for (int j = 0; j < 4; ++j) acc[i][j] = 0.f;

#pragma unroll
  for (int k = 0; k < 64; ++k) {
    float h0 = Hs[r0 + 0][k];
    float h1 = Hs[r0 + 1][k];
    float h2 = Hs[r0 + 2][k];
    float h3 = Hs[r0 + 3][k];
    float4 wv = *reinterpret_cast<const float4*>(&Ws[k][c0]);
    acc[0][0] = fmaf(h0, wv.x, acc[0][0]);
    acc[0][1] = fmaf(h0, wv.y, acc[0][1]);
    acc[0][2] = fmaf(h0, wv.z, acc[0][2]);
    acc[0][3] = fmaf(h0, wv.w, acc[0][3]);
    acc[1][0] = fmaf(h1, wv.x, acc[1][0]);
    acc[1][1] = fmaf(h1, wv.y, acc[1][1]);
    acc[1][2] = fmaf(h1, wv.z, acc[1][2]);
    acc[1][3] = fmaf(h1, wv.w, acc[1][3]);
    acc[2][0] = fmaf(h2, wv.x, acc[2][0]);
    acc[2][1] = fmaf(h2, wv.y, acc[2][1]);
    acc[2][2] = fmaf(h2, wv.z, acc[2][2]);
    acc[2][3] = fmaf(h2, wv.w, acc[2][3]);
    acc[3][0] = fmaf(h3, wv.x, acc[3][0]);
    acc[3][1] = fmaf(h3, wv.y, acc[3][1]);
    acc[3][2] = fmaf(h3, wv.z, acc[3][2]);
    acc[3][3] = fmaf(h3, wv.w, acc[3][3]);
  }

  float4 bv = make_float4(0.f, 0.f, 0.f, 0.f);
  if (fuse) bv = *reinterpret_cast<const float4*>(bias + c0);
#pragma unroll
  for (int i = 0; i < 4; ++i) {
    long long row = (long long)row0 + r0 + i;
    if (row >= n) break;
    float4 o = make_float4(acc[i][0], acc[i][1], acc[i][2], acc[i][3]);
    if (fuse) {
      o.x = fmaxf(o.x + bv.x, 0.f);
      o.y = fmaxf(o.y + bv.y, 0.f);
      o.z = fmaxf(o.z + bv.z, 0.f);
      o.w = fmaxf(o.w + bv.w, 0.f);
    }
    *reinterpret_cast<float4*>(T + (size_t)row * DD + c0) = o;
  }
}

// ---- CSR aggregation: out[n,:] = sum_j val[j]*T[col[j],:] + b (relu opt) ---
// one wave (64 lanes) per node, lane = feature dim. No atomics.
__global__ __launch_bounds__(256) void aggregate_kernel(
    const float* __restrict__ T, const int* __restrict__ offs,
    const int* __restrict__ col, const float* __restrict__ val,
    const float* __restrict__ bias, float* __restrict__ out,
    int n, int relu) {
  int gid = blockIdx.x * blockDim.x + threadIdx.x;
  int wid = gid >> 6;
  int lane = threadIdx.x & 63;
  if (wid >= n) return;
  int j0 = offs[wid], j1 = offs[wid + 1];
  float acc = 0.f;
  int j = j0;
  for (; j + 4 <= j1; j += 4) {
    int c0 = col[j], c1 = col[j + 1], c2 = col[j + 2], c3 = col[j + 3];
    float v0 = val[j], v1 = val[j + 1], v2 = val[j + 2], v3 = val[j + 3];
    float f0 = T[(size_t)c0 * DD + lane];
    float f1 = T[(size_t)c1 * DD + lane];
    float f2 = T[(size_t)c2 * DD + lane];
    float f3 = T[(size_t)c3 * DD + lane];
    acc = fmaf(v0, f0, acc);
    acc = fmaf(v1, f1, acc);
    acc = fmaf(v2, f2, acc);
    acc = fmaf(v3, f3, acc);
  }
  for (; j < j1; ++j)
    acc = fmaf(val[j], T[(size_t)col[j] * DD + lane], acc);
  acc += bias[lane];
  if (relu) acc = fmaxf(acc, 0.f);
  out[(size_t)wid * DD + lane] = acc;
}

// ---------------------------------------------------------------------------
extern "C" void kernel_launch(void* const* d_in, const int* in_sizes, int n_in,
                              void* d_out, int out_size, void* d_ws, size_t ws_size,
                              hipStream_t stream) {
  const float* x   = (const float*)d_in[0];
  const void*  eix = d_in[1];
  const float* Win = (const float*)d_in[2];
  const float* bin = (const float*)d_in[3];
  const float* W1  = (const float*)d_in[4];
  const float* b1  = (const float*)d_in[5];
  const float* W2  = (const float*)d_in[6];
  const float* b2  = (const float*)d_in[7];
  const float* W3  = (const float*)d_in[8];
  const float* b3  = (const float*)d_in[9];

  int n = in_sizes[0] / DD;
  int E = in_sizes[1] / 2;
  int M = E + n;

  char* w = (char*)d_ws;
  auto carve = [&](size_t bytes) {
    char* p = w;
    w += (bytes + 255) & ~(size_t)255;
    return p;
  };
  int*   flag   = (int*)carve(4);
  int*   deg    = (int*)carve((size_t)n * 4);
  float* dinv   = (float*)carve((size_t)n * 4);
  int*   incl   = (int*)carve((size_t)n * 4);
  int*   bsum   = (int*)carve(4096);
  int*   boff   = (int*)carve(4096);
  int*   offs   = (int*)carve((size_t)(n + 1) * 4);
  int*   cursor = (int*)carve((size_t)n * 4);
  int*   src32  = (int*)carve((size_t)E * 4);
  int*   dst32  = (int*)carve((size_t)E * 4);
  int*   col    = (int*)carve((size_t)M * 4);
  float* val    = (float*)carve((size_t)M * 4);
  float* hbuf   = (float*)carve((size_t)n * DD * 4);
  float* tbuf   = (float*)carve((size_t)n * DD * 4);

  int nb = (n + 1023) / 1024;

  detect_i64_kernel<<<1, 64, 0, stream>>>((const unsigned int*)eix, E, flag);
  init_deg_kernel<<<(n + 255) / 256, 256, 0, stream>>>(deg, n);
  convert_count_kernel<<<(E + 255) / 256, 256, 0, stream>>>(eix, E, src32, dst32, deg, flag);
  dinv_kernel<<<(n + 255) / 256, 256, 0, stream>>>(deg, dinv, n);
  scan_tile_kernel<<<nb, 1024, 0, stream>>>(deg, incl, bsum, n);
  scan_blocks_kernel<<<1, 64, 0, stream>>>(bsum, boff, nb, offs + n);
  scan_final_kernel<<<(n + 255) / 256, 256, 0, stream>>>(incl, deg, boff, offs, cursor, n);
  scatter_kernel<<<(M + 255) / 256, 256, 0, stream>>>(src32, dst32, dinv, cursor, col, val, E, n);

  int gemm_grid = (n + 63) / 64;
  int agg_grid  = (n * 64 + 255) / 256;

  // layer 0: h = relu(x @ W_in + b_in)
  gemm_kernel<<<gemm_grid, 256, 0, stream>>>(x, Win, bin, hbuf, n, 1);

  // conv1: h = relu(agg(h @ W1) + b1)
  gemm_kernel<<<gemm_grid, 256, 0, stream>>>(hbuf, W1, nullptr, tbuf, n, 0);
  aggregate_kernel<<<agg_grid, 256, 0, stream>>>(tbuf, offs, col, val, b1, hbuf, n, 1);

  // conv2: h = relu(agg(h @ W2) + b2)
  gemm_kernel<<<gemm_grid, 256, 0, stream>>>(hbuf, W2, nullptr, tbuf, n, 0);
  aggregate_kernel<<<agg_grid, 256, 0, stream>>>(tbuf, offs, col, val, b2, hbuf, n, 1);

  // conv3: out = agg(h @ W3) + b3   (no relu)
  gemm_kernel<<<gemm_grid, 256, 0, stream>>>(hbuf, W3, nullptr, tbuf, n, 0);
  aggregate_kernel<<<agg_grid, 256, 0, stream>>>(tbuf, offs, col, val, b3, (float*)d_out, n, 0);
}